// Round 8
// baseline (161.435 us; speedup 1.0000x reference)
//
#include <hip/hip_runtime.h>

#define LQ 1024
#define NP 32
#define CC 2.0611536224385579e-9f   // expf(-20)

typedef __attribute__((ext_vector_type(8))) short short8v;
typedef __attribute__((ext_vector_type(4))) float f32x4;

__device__ __forceinline__ unsigned short bf16hi(float f) {
  unsigned u = __float_as_uint(f);
  u += 0x7fffu + ((u >> 16) & 1u);
  return (unsigned short)(u >> 16);
}
__device__ __forceinline__ float bf16tof(unsigned short b) {
  return __uint_as_float(((unsigned)b) << 16);
}
#define SWZD(d) (((d) & 7) ^ ((d) >> 3))

// ---------------------------------------------------------------------------
// Fully fused: one block per (b,h,row-group of 64). Phase 1: per-block V
// column-sum (L2-amortized across the 16 same-bh blocks). Phase 2: flash-style
// masked attention over the <=3 live 64-chunks of the 192-wide window.
// bf16x2 QK^T (3 MFMA terms) + bf16 PV, fp32 accumulate, exact z.
// ---------------------------------------------------------------------------
__global__ __launch_bounds__(256, 4) void attn_kernel(const float* __restrict__ Q,
                                                      const float* __restrict__ K,
                                                      const float* __restrict__ V,
                                                      const int* __restrict__ starts,
                                                      float* __restrict__ out) {
  __shared__ unsigned short Kh[4096], Kl[4096], Vt[4096], Plds[4096];
  __shared__ float red[16][64];
  __shared__ float colsum[64];
  __shared__ int lotab[64], hitab[64];

  const int tid = threadIdx.x;
  const int lane = tid & 63;
  const int w = tid >> 6;
  const int lr = lane & 15, lg = lane >> 4;
  const int blk = ((blockIdx.x & 7) << 7) | (blockIdx.x >> 3);  // XCD swizzle
  const int grp = blk & 15, bh = blk >> 4;
  const int h = bh & 7, b = bh >> 3;
  const int L0 = grp << 6;
  int w0 = L0 - 64; w0 = w0 < 0 ? 0 : (w0 > LQ - 192 ? LQ - 192 : w0);

  const float* Kb = K + (size_t)b * LQ * 512 + h * 64;
  const float* Vb = V + (size_t)b * LQ * 512 + h * 64;

  // per-lane mask bounds for row L0+lane (waves compute identical values)
  int lo_l = 0x7fffffff, hi_l = 0;
#pragma unroll
  for (int p = 0; p < NP; ++p) {
    int sp = starts[p];
    if ((unsigned)(L0 + lane - sp) < 64u) { lo_l = min(lo_l, sp); hi_l = max(hi_l, sp + 64); }
  }
  if (tid < 64) { lotab[tid] = lo_l; hitab[tid] = hi_l; }

  int rlo = lo_l, rhi = hi_l;
#pragma unroll
  for (int off = 32; off; off >>= 1) {
    rlo = min(rlo, __shfl_xor(rlo, off));
    rhi = max(rhi, __shfl_xor(rhi, off));
  }
  rlo = __builtin_amdgcn_readfirstlane(rlo);
  rhi = __builtin_amdgcn_readfirstlane(rhi);

  int csl[3], ncs = 0;
#pragma unroll
  for (int c = 0; c < 3; ++c) {
    const int cs = w0 + c * 64;
    if (cs < rhi && cs + 64 > rlo) csl[ncs++] = cs;
  }

  const int c4 = tid & 15;
  float4 kreg[4], vreg[4];
  auto gload = [&](int cs) {
#pragma unroll
    for (int t = 0; t < 4; ++t) {
      const int sr = t * 16 + (tid >> 4);
      kreg[t] = *(const float4*)(Kb + (size_t)(cs + sr) * 512 + c4 * 4);
      vreg[t] = *(const float4*)(Vb + (size_t)(cs + sr) * 512 + c4 * 4);
    }
  };
  auto lwrite = [&]() {
#pragma unroll
    for (int t = 0; t < 4; ++t) {
      const int sr = t * 16 + (tid >> 4);
      ushort4 h4, l4;
      float fk[4] = {kreg[t].x, kreg[t].y, kreg[t].z, kreg[t].w};
#pragma unroll
      for (int i = 0; i < 4; ++i) {
        unsigned short hb = bf16hi(fk[i]);
        ((unsigned short*)&h4)[i] = hb;
        ((unsigned short*)&l4)[i] = bf16hi(fk[i] - bf16tof(hb));
      }
      const int kidx = sr * 64 + (((c4 >> 1) ^ (sr & 7)) * 8) + (c4 & 1) * 4;
      *(ushort4*)&Kh[kidx] = h4;
      *(ushort4*)&Kl[kidx] = l4;
      float fv[4] = {vreg[t].x, vreg[t].y, vreg[t].z, vreg[t].w};
#pragma unroll
      for (int i = 0; i < 4; ++i) {
        const int d = c4 * 4 + i;
        Vt[d * 64 + (((sr >> 3) ^ SWZD(d)) * 8) + (sr & 7)] = bf16hi(fv[i]);
      }
    }
  };

  if (ncs) gload(csl[0]);          // window chunk 0 in flight

  // Q fragments (fp32 -> bf16 hi/lo), row = L0 + w*16 + lr
  const float* Qrow = Q + ((size_t)b * LQ + L0 + w * 16 + lr) * 512 + h * 64;
  short8v qhi[2], qlo[2];
#pragma unroll
  for (int ks = 0; ks < 2; ++ks) {
    float4 a = *(const float4*)(Qrow + ks * 32 + lg * 8);
    float4 c = *(const float4*)(Qrow + ks * 32 + lg * 8 + 4);
    short8v hi8, lo8;
    float fv[8] = {a.x, a.y, a.z, a.w, c.x, c.y, c.z, c.w};
#pragma unroll
    for (int i = 0; i < 8; ++i) {
      unsigned short hb = bf16hi(fv[i]);
      hi8[i] = (short)hb;
      lo8[i] = (short)bf16hi(fv[i] - bf16tof(hb));
    }
    qhi[ks] = hi8; qlo[ks] = lo8;
  }

  // ---- phase 1: V column-sum over all 1024 rows (coalesced, L2-amortized)
  {
    float4 facc = make_float4(0.f, 0.f, 0.f, 0.f);
    const float* Vs = Vb + (size_t)(tid >> 4) * 512 + c4 * 4;
#pragma unroll 8
    for (int t = 0; t < 64; ++t) {
      const float4 v = *(const float4*)(Vs + (size_t)t * 16 * 512);
      facc.x += v.x; facc.y += v.y; facc.z += v.z; facc.w += v.w;
    }
    *(float4*)&red[tid >> 4][c4 * 4] = facc;
  }
  __syncthreads();
  if (tid < 64) {
    float s = 0.f;
#pragma unroll
    for (int g = 0; g < 16; ++g) s += red[g][tid];
    colsum[tid] = s;
  }

  if (ncs) {
    lwrite();                       // chunk 0 regs -> LDS
    if (ncs > 1) gload(csl[1]);     // chunk 1 in flight
  }
  __syncthreads();                  // planes + colsum ready

  int lo_r[4], hi_r[4];
#pragma unroll
  for (int r = 0; r < 4; ++r) {
    lo_r[r] = lotab[w * 16 + lg * 4 + r];
    hi_r[r] = hitab[w * 16 + lg * 4 + r];
  }

  f32x4 oacc[4];
  float zloc[4] = {0.f, 0.f, 0.f, 0.f};
#pragma unroll
  for (int n = 0; n < 4; ++n) oacc[n] = (f32x4){0.f, 0.f, 0.f, 0.f};

  for (int i = 0; i < ncs; ++i) {
    const int cs = csl[i];
    f32x4 sacc[4];
#pragma unroll
    for (int n = 0; n < 4; ++n) sacc[n] = (f32x4){0.f, 0.f, 0.f, 0.f};

#pragma unroll
    for (int ks = 0; ks < 2; ++ks) {
#pragma unroll
      for (int n = 0; n < 4; ++n) {
        const int srow = n * 16 + lr;
        const int idx = srow * 64 + (((ks * 4 + lg) ^ (srow & 7)) * 8);
        const short8v kbh = *(const short8v*)&Kh[idx];
        const short8v kbl = *(const short8v*)&Kl[idx];
        sacc[n] = __builtin_amdgcn_mfma_f32_16x16x32_bf16(qhi[ks], kbh, sacc[n], 0, 0, 0);
        sacc[n] = __builtin_amdgcn_mfma_f32_16x16x32_bf16(qhi[ks], kbl, sacc[n], 0, 0, 0);
        sacc[n] = __builtin_amdgcn_mfma_f32_16x16x32_bf16(qlo[ks], kbh, sacc[n], 0, 0, 0);
      }
    }

#pragma unroll
    for (int n = 0; n < 4; ++n) {
#pragma unroll
      for (int r = 0; r < 4; ++r) {
        const int sg = cs + n * 16 + lr;
        float p = 0.f;
        if (sg >= lo_r[r] && sg < hi_r[r]) p = __expf(sacc[n][r] - 20.f) - CC;
        const unsigned short pb16 = bf16hi(p);
        zloc[r] += bf16tof(pb16);
        const int prow = w * 16 + lg * 4 + r;
        const int sl = n * 16 + lr;
        Plds[prow * 64 + (((sl >> 3) ^ ((prow & 7) ^ (prow >> 3))) * 8) + (sl & 7)] = pb16;
      }
    }

#pragma unroll
    for (int ks = 0; ks < 2; ++ks) {
      const int prow = w * 16 + lr;
      const short8v pa = *(const short8v*)
          &Plds[prow * 64 + (((ks * 4 + lg) ^ ((prow & 7) ^ (prow >> 3))) * 8)];
#pragma unroll
      for (int n = 0; n < 4; ++n) {
        const int d = n * 16 + lr;
        const short8v vb = *(const short8v*)&Vt[d * 64 + (((ks * 4 + lg) ^ SWZD(d)) * 8)];
        oacc[n] = __builtin_amdgcn_mfma_f32_16x16x32_bf16(pa, vb, oacc[n], 0, 0, 0);
      }
    }

    if (i + 1 < ncs) {
      __syncthreads();              // done reading current planes
      lwrite();                     // chunk i+1 regs -> LDS
      if (i + 2 < ncs) gload(csl[i + 2]);
      __syncthreads();              // planes ready
    }
  }

  // z: reduce over the 16 column-lanes
#pragma unroll
  for (int r = 0; r < 4; ++r) {
#pragma unroll
    for (int off = 1; off < 16; off <<= 1) zloc[r] += __shfl_xor(zloc[r], off, 64);
  }

  float sv[4];
#pragma unroll
  for (int n = 0; n < 4; ++n) sv[n] = colsum[n * 16 + lr];

  float* Ob = out + ((size_t)b * LQ + L0 + w * 16 + lg * 4) * 512 + h * 64;
#pragma unroll
  for (int r = 0; r < 4; ++r) {
    const float invz = 1.f / (zloc[r] + 1024.f * CC);
#pragma unroll
    for (int n = 0; n < 4; ++n)
      Ob[(size_t)r * 512 + n * 16 + lr] = (oacc[n][r] + CC * sv[n]) * invz;
  }
}

// ---------------------------------------------------------------------------
extern "C" void kernel_launch(void* const* d_in, const int* in_sizes, int n_in,
                              void* d_out, int out_size, void* d_ws, size_t ws_size,
                              hipStream_t stream) {
  const float* Q      = (const float*)d_in[0];
  const float* K      = (const float*)d_in[1];
  const float* V      = (const float*)d_in[2];
  const int*   starts = (const int*)d_in[3];
  float* out = (float*)d_out;

  attn_kernel<<<1024, 256, 0, stream>>>(Q, K, V, starts, out);
}

// Round 10
// 111.814 us; speedup vs baseline: 1.4438x; 1.4438x over previous
//
#include <hip/hip_runtime.h>

#define LQ 1024
#define NP 32
#define CC 2.0611536224385579e-9f   // expf(-20)

typedef __attribute__((ext_vector_type(8))) short short8v;
typedef __attribute__((ext_vector_type(4))) float f32x4;

__device__ __forceinline__ unsigned short bf16hi(float f) {
  unsigned u = __float_as_uint(f);
  u += 0x7fffu + ((u >> 16) & 1u);
  return (unsigned short)(u >> 16);
}
__device__ __forceinline__ float bf16tof(unsigned short b) {
  return __uint_as_float(((unsigned)b) << 16);
}
#define SWZD(d) (((d) & 7) ^ ((d) >> 3))

// ---------------------------------------------------------------------------
// sumv: partial[(bh*16+sc)*64 + d] = sum_{s in chunk sc} V[b][s][h*64+d]
// 1024 blocks x 256 threads, 16 KB coalesced read per block.
// ---------------------------------------------------------------------------
__global__ __launch_bounds__(256) void sumv_kernel(const float* __restrict__ V,
                                                   float* __restrict__ partial) {
  __shared__ float red[16][64];
  const int blk = blockIdx.x;
  const int sc = blk & 15, h = (blk >> 4) & 7, b = blk >> 7;
  const int tid = threadIdx.x;
  const int c4 = tid & 15;
  const float* Vb = V + ((size_t)b * LQ + sc * 64) * 512 + h * 64;
  float4 facc = make_float4(0.f, 0.f, 0.f, 0.f);
#pragma unroll
  for (int t = 0; t < 4; ++t) {
    const int sr = t * 16 + (tid >> 4);
    const float4 v = *(const float4*)(Vb + (size_t)sr * 512 + c4 * 4);
    facc.x += v.x; facc.y += v.y; facc.z += v.z; facc.w += v.w;
  }
  *(float4*)&red[tid >> 4][c4 * 4] = facc;
  __syncthreads();
  if (tid < 64) {
    float s = 0.f;
#pragma unroll
    for (int g = 0; g < 16; ++g) s += red[g][tid];
    partial[(size_t)blk * 64 + tid] = s;
  }
}

// ---------------------------------------------------------------------------
// attn: block per (b,h,row-group). K/V fp32 -> regs (one chunk ahead) ->
// convert -> 25 KB LDS (P reuses the Klo plane after QK^T) -> bf16x2 QK^T +
// bf16 PV. Dead-chunk skip; XCD-swizzled grid.
// ---------------------------------------------------------------------------
__global__ __launch_bounds__(256) void attn_kernel(const float* __restrict__ Q,
                                                   const float* __restrict__ K,
                                                   const float* __restrict__ V,
                                                   const int* __restrict__ starts,
                                                   const float* __restrict__ partial,
                                                   float* __restrict__ out) {
  __shared__ unsigned short Kh[4096], Kl[4096], Vt[4096];
  __shared__ int lotab[64], hitab[64];
  unsigned short* Plds = Kl;     // P overwrites the Klo plane after QK^T

  const int tid = threadIdx.x;
  const int lane = tid & 63;
  const int w = tid >> 6;
  const int lr = lane & 15, lg = lane >> 4;
  const int blk = ((blockIdx.x & 7) << 7) | (blockIdx.x >> 3);  // XCD swizzle
  const int grp = blk & 15, bh = blk >> 4;
  const int h = bh & 7, b = bh >> 3;
  const int L0 = grp << 6;
  int w0 = L0 - 64; w0 = w0 < 0 ? 0 : (w0 > LQ - 192 ? LQ - 192 : w0);

  const float* Kb = K + (size_t)b * LQ * 512 + h * 64;
  const float* Vb = V + (size_t)b * LQ * 512 + h * 64;

  // Q loads first: longest-latency independent work up front.
  const float* Qrow = Q + ((size_t)b * LQ + L0 + w * 16 + lr) * 512 + h * 64;
  float4 qraw[4];
#pragma unroll
  for (int ks = 0; ks < 2; ++ks) {
    qraw[ks * 2]     = *(const float4*)(Qrow + ks * 32 + lg * 8);
    qraw[ks * 2 + 1] = *(const float4*)(Qrow + ks * 32 + lg * 8 + 4);
  }

  // per-lane mask bounds for row L0+lane
  int lo_l = 0x7fffffff, hi_l = 0;
#pragma unroll
  for (int p = 0; p < NP; ++p) {
    int sp = starts[p];
    if ((unsigned)(L0 + lane - sp) < 64u) { lo_l = min(lo_l, sp); hi_l = max(hi_l, sp + 64); }
  }
  if (tid < 64) { lotab[tid] = lo_l; hitab[tid] = hi_l; }

  int rlo = lo_l, rhi = hi_l;
#pragma unroll
  for (int off = 32; off; off >>= 1) {
    rlo = min(rlo, __shfl_xor(rlo, off));
    rhi = max(rhi, __shfl_xor(rhi, off));
  }
  rlo = __builtin_amdgcn_readfirstlane(rlo);
  rhi = __builtin_amdgcn_readfirstlane(rhi);

  int csl[3], ncs = 0;
#pragma unroll
  for (int c = 0; c < 3; ++c) {
    const int cs = w0 + c * 64;
    if (cs < rhi && cs + 64 > rlo) csl[ncs++] = cs;
  }

  const int c4 = tid & 15;
  float4 kreg[4], vreg[4];
  auto gload = [&](int cs) {
#pragma unroll
    for (int t = 0; t < 4; ++t) {
      const int sr = t * 16 + (tid >> 4);
      kreg[t] = *(const float4*)(Kb + (size_t)(cs + sr) * 512 + c4 * 4);
      vreg[t] = *(const float4*)(Vb + (size_t)(cs + sr) * 512 + c4 * 4);
    }
  };
  auto lwrite = [&]() {
#pragma unroll
    for (int t = 0; t < 4; ++t) {
      const int sr = t * 16 + (tid >> 4);
      ushort4 h4, l4;
      float fk[4] = {kreg[t].x, kreg[t].y, kreg[t].z, kreg[t].w};
#pragma unroll
      for (int i = 0; i < 4; ++i) {
        unsigned short hb = bf16hi(fk[i]);
        ((unsigned short*)&h4)[i] = hb;
        ((unsigned short*)&l4)[i] = bf16hi(fk[i] - bf16tof(hb));
      }
      const int kidx = sr * 64 + (((c4 >> 1) ^ (sr & 7)) * 8) + (c4 & 1) * 4;
      *(ushort4*)&Kh[kidx] = h4;
      *(ushort4*)&Kl[kidx] = l4;
      float fv[4] = {vreg[t].x, vreg[t].y, vreg[t].z, vreg[t].w};
#pragma unroll
      for (int i = 0; i < 4; ++i) {
        const int d = c4 * 4 + i;
        Vt[d * 64 + (((sr >> 3) ^ SWZD(d)) * 8) + (sr & 7)] = bf16hi(fv[i]);
      }
    }
  };

  if (ncs) gload(csl[0]);

  // Q fp32 -> bf16 hi/lo fragments
  short8v qhi[2], qlo[2];
#pragma unroll
  for (int ks = 0; ks < 2; ++ks) {
    const float4 a = qraw[ks * 2], c = qraw[ks * 2 + 1];
    short8v hi8, lo8;
    float fv[8] = {a.x, a.y, a.z, a.w, c.x, c.y, c.z, c.w};
#pragma unroll
    for (int i = 0; i < 8; ++i) {
      unsigned short hb = bf16hi(fv[i]);
      hi8[i] = (short)hb;
      lo8[i] = (short)bf16hi(fv[i] - bf16tof(hb));
    }
    qhi[ks] = hi8; qlo[ks] = lo8;
  }

  if (ncs) {
    lwrite();
    if (ncs > 1) gload(csl[1]);
  }
  __syncthreads();

  int lo_r[4], hi_r[4];
#pragma unroll
  for (int r = 0; r < 4; ++r) {
    lo_r[r] = lotab[w * 16 + lg * 4 + r];
    hi_r[r] = hitab[w * 16 + lg * 4 + r];
  }

  f32x4 oacc[4];
  float zloc[4] = {0.f, 0.f, 0.f, 0.f};
#pragma unroll
  for (int n = 0; n < 4; ++n) oacc[n] = (f32x4){0.f, 0.f, 0.f, 0.f};

  for (int i = 0; i < ncs; ++i) {
    const int cs = csl[i];
    f32x4 sacc[4];
#pragma unroll
    for (int n = 0; n < 4; ++n) sacc[n] = (f32x4){0.f, 0.f, 0.f, 0.f};

#pragma unroll
    for (int ks = 0; ks < 2; ++ks) {
#pragma unroll
      for (int n = 0; n < 4; ++n) {
        const int srow = n * 16 + lr;
        const int idx = srow * 64 + (((ks * 4 + lg) ^ (srow & 7)) * 8);
        const short8v kbh = *(const short8v*)&Kh[idx];
        const short8v kbl = *(const short8v*)&Kl[idx];
        sacc[n] = __builtin_amdgcn_mfma_f32_16x16x32_bf16(qhi[ks], kbh, sacc[n], 0, 0, 0);
        sacc[n] = __builtin_amdgcn_mfma_f32_16x16x32_bf16(qhi[ks], kbl, sacc[n], 0, 0, 0);
        sacc[n] = __builtin_amdgcn_mfma_f32_16x16x32_bf16(qlo[ks], kbh, sacc[n], 0, 0, 0);
      }
    }

    __syncthreads();                // all waves done reading Klo before P lands in it

#pragma unroll
    for (int n = 0; n < 4; ++n) {
#pragma unroll
      for (int r = 0; r < 4; ++r) {
        const int sg = cs + n * 16 + lr;
        float p = 0.f;
        if (sg >= lo_r[r] && sg < hi_r[r]) p = __expf(sacc[n][r] - 20.f) - CC;
        const unsigned short pb16 = bf16hi(p);
        zloc[r] += bf16tof(pb16);
        const int prow = w * 16 + lg * 4 + r;
        const int sl = n * 16 + lr;
        Plds[prow * 64 + (((sl >> 3) ^ ((prow & 7) ^ (prow >> 3))) * 8) + (sl & 7)] = pb16;
      }
    }

    // P rows written/read within the same wave -> no barrier needed here
#pragma unroll
    for (int ks = 0; ks < 2; ++ks) {
      const int prow = w * 16 + lr;
      const short8v pa = *(const short8v*)
          &Plds[prow * 64 + (((ks * 4 + lg) ^ ((prow & 7) ^ (prow >> 3))) * 8)];
#pragma unroll
      for (int n = 0; n < 4; ++n) {
        const int d = n * 16 + lr;
        const short8v vb = *(const short8v*)&Vt[d * 64 + (((ks * 4 + lg) ^ SWZD(d)) * 8)];
        oacc[n] = __builtin_amdgcn_mfma_f32_16x16x32_bf16(pa, vb, oacc[n], 0, 0, 0);
      }
    }

    if (i + 1 < ncs) {
      __syncthreads();              // done reading current planes (incl. P in Klo)
      lwrite();                     // chunk i+1 regs -> LDS
      if (i + 2 < ncs) gload(csl[i + 2]);
      __syncthreads();              // planes ready
    }
  }

  // z: reduce over the 16 column-lanes
#pragma unroll
  for (int r = 0; r < 4; ++r) {
#pragma unroll
    for (int off = 1; off < 16; off <<= 1) zloc[r] += __shfl_xor(zloc[r], off, 64);
  }

  // background sumV
  float sv[4];
#pragma unroll
  for (int n = 0; n < 4; ++n) {
    float s = 0.f;
#pragma unroll
    for (int sc2 = 0; sc2 < 16; ++sc2)
      s += partial[(size_t)bh * 1024 + sc2 * 64 + n * 16 + lr];
    sv[n] = s;
  }

  float* Ob = out + ((size_t)b * LQ + L0 + w * 16 + lg * 4) * 512 + h * 64;
#pragma unroll
  for (int r = 0; r < 4; ++r) {
    const float invz = 1.f / (zloc[r] + 1024.f * CC);
#pragma unroll
    for (int n = 0; n < 4; ++n)
      Ob[(size_t)r * 512 + n * 16 + lr] = (oacc[n][r] + CC * sv[n]) * invz;
  }
}

// ---------------------------------------------------------------------------
extern "C" void kernel_launch(void* const* d_in, const int* in_sizes, int n_in,
                              void* d_out, int out_size, void* d_ws, size_t ws_size,
                              hipStream_t stream) {
  const float* Q      = (const float*)d_in[0];
  const float* K      = (const float*)d_in[1];
  const float* V      = (const float*)d_in[2];
  const int*   starts = (const int*)d_in[3];
  float* out     = (float*)d_out;
  float* partial = (float*)d_ws;               // 64*16*64 fp32 = 256 KB

  sumv_kernel<<<1024, 256, 0, stream>>>(V, partial);
  attn_kernel<<<1024, 256, 0, stream>>>(Q, K, V, starts, partial, out);
}